// Round 1
// baseline (93.203 us; speedup 1.0000x reference)
//
#include <hip/hip_runtime.h>
#include <cstdint>

#define BB 2048
#define KK 200
#define DD 256
#define AA 13
#define NBOND 5
#define EP 200          // eT bf16 k-pitch (shorts): 400B rows, 16B-aligned, ~2-way banks
#define NBLK (BB / 2)   // 1024 blocks x 4 waves; 2 waves cooperate per molecule

typedef __attribute__((ext_vector_type(8))) short bf16x8;
typedef __attribute__((ext_vector_type(4))) short bf16x4;
typedef __attribute__((ext_vector_type(4))) float f32x4;

// smem layout (bytes), hand-placed so Phase-B spill reads (col>=13 lanes, k>=200
// chunks -- all multiplied by w2f==0 or gated on write) stay inside the block:
//   [0,     11200)  eTb: 2 molecules x 14 rows x EP shorts (row 13 = guard)
//   [11200, 12552)  rsw: 2 x 169 floats
//   [12560, 45328)  xs : 4 waves x 16*256 shorts (per-wave x staging, 16B aligned)
#define ETB_OFF 0
#define RSW_OFF 11200
#define XS_OFF  12560
#define SMEM_BYTES 45328

// fp32 -> bf16 RNE, branchless (R6 lesson: beats __float22bfloat162_rn+union).
__device__ __forceinline__ short f2bf(float f) {
    unsigned u = __builtin_bit_cast(unsigned, f);
    unsigned r = (u + 0x7fffu + ((u >> 16) & 1u)) >> 16;
    return (short)r;
}

__device__ __forceinline__ bf16x8 cvt8(float4 a, float4 b) {
    bf16x8 f;
    f[0] = f2bf(a.x); f[1] = f2bf(a.y); f[2] = f2bf(a.z); f[3] = f2bf(a.w);
    f[4] = f2bf(b.x); f[5] = f2bf(b.y); f[6] = f2bf(b.z); f[7] = f2bf(b.w);
    return f;
}

__device__ __forceinline__ bf16x4 pack4(f32x4 a) {
    bf16x4 f;
    f[0] = f2bf(a[0]); f[1] = f2bf(a[1]); f[2] = f2bf(a[2]); f[3] = f2bf(a[3]);
    return f;
}

__device__ __forceinline__ bf16x4 pack4f(float4 a) {
    bf16x4 f;
    f[0] = f2bf(a.x); f[1] = f2bf(a.y); f[2] = f2bf(a.z); f[3] = f2bf(a.w);
    return f;
}

// R12 CHANGE: 2 waves per molecule (tiles 0..6 / 7..12) -> 4096 waves total,
// 12 waves/CU (3 blocks/CU: LDS 45.3KB, VGPR capped 168 via launch_bounds(256,3);
// w2f load deferred past the barrier to drop 28 regs of Phase-A dead weight).
// Previous structure was grid-capped at 8 waves/CU and ran at 4.87 TB/s (77% of
// the copy ceiling) -- bursty per-wave issue with only 2 streams/SIMD let the
// HBM queue drain intermittently.
__global__ __launch_bounds__(256, 3) void fused(const float* __restrict__ x,
                                                const float* __restrict__ w1,
                                                const float* __restrict__ b1,
                                                const float* __restrict__ w2,
                                                const float* __restrict__ b2,
                                                const float* __restrict__ flw,
                                                const float* __restrict__ flb,
                                                float* __restrict__ out) {
    __shared__ __align__(16) char smem[SMEM_BYTES];

    const int tid  = threadIdx.x;
    const int lane = tid & 63;
    const int wv   = tid >> 6;
    const int mol  = wv >> 1;          // molecule within block (0,1)
    const int half = wv & 1;           // K-tile half (0: tiles 0..6, 1: 7..12)
    const int col  = lane & 15;        // fragment row AND output col (a)
    const int kg   = lane >> 4;        // k-group 0..3
    const long b   = (long)blockIdx.x * 2 + mol;
    const float* xbase = x + b * (size_t)(KK * DD);

    short* eTb = (short*)(smem + ETB_OFF) + mol * (14 * EP);
    float* rsw = (float*)(smem + RSW_OFF) + mol * 169;
    char*  xsw = smem + XS_OFF + wv * (16 * 256 * 2);

    const int T0 = half ? 7 : 0;
    const int T1 = half ? 13 : 7;

    // guard row: eTb[13][0..31] = 0 absorbs col=12's k>=200 spill reads (x0 in MFMA)
    if (!half && lane < 32) eTb[13 * EP + lane] = 0;

    // ---- prologue: first tile of this wave's half, contiguous 1KB loads ------
    float4 xa[8], xb[8];
    {
        const int rb = T0 * 16;
        #pragma unroll
        for (int r = 0; r < 8; ++r)
            xa[r] = *(const float4*)(xbase + (size_t)min(rb + r, KK - 1) * DD + lane * 4);
        #pragma unroll
        for (int r = 0; r < 8; ++r)
            xb[r] = *(const float4*)(xbase + (size_t)min(rb + 8 + r, KK - 1) * DD + lane * 4);
    }

    // ---- W1 B-fragments resident, natural k-order (lane holds W1^T[k][col]) -
    bf16x8 bfrag[8];
    if (col < AA) {
        const float* wp = w1 + col * DD + kg * 8;
        #pragma unroll
        for (int ks = 0; ks < 8; ++ks)
            bfrag[ks] = cvt8(*(const float4*)(wp + ks * 32),
                             *(const float4*)(wp + ks * 32 + 4));
    } else {
        #pragma unroll
        for (int ks = 0; ks < 8; ++ks) {
            bf16x8 z;
            #pragma unroll
            for (int j = 0; j < 8; ++j) z[j] = 0;
            bfrag[ks] = z;
        }
    }
    const float bias = (col < AA) ? b1[col] : 0.0f;

    const int wbyte = lane * 8;                       // unswizzled write chunk
    const int rswz  = (col & 7) << 4;                 // read swizzle constant

    // ---- Phase A: this wave's tiles; regs are the double-buffer across tiles -
    for (int t = T0; t < T1; ++t) {
        // cvt + swizzled ds_write (waits xa loads, then xb loads)
        #pragma unroll
        for (int r = 0; r < 8; ++r)
            *(bf16x4*)(xsw + r * 512 + (wbyte ^ ((r & 7) << 4))) = pack4f(xa[r]);
        #pragma unroll
        for (int r = 0; r < 8; ++r) {
            const int rr = 8 + r;
            *(bf16x4*)(xsw + rr * 512 + (wbyte ^ ((rr & 7) << 4))) = pack4f(xb[r]);
        }

        // issue next tile's 16 contiguous loads (fly through MFMA phase)
        if (t + 1 < T1) {
            const int rb = (t + 1) * 16;
            #pragma unroll
            for (int r = 0; r < 8; ++r)
                xa[r] = *(const float4*)(xbase + (size_t)min(rb + r, KK - 1) * DD + lane * 4);
            #pragma unroll
            for (int r = 0; r < 8; ++r)
                xb[r] = *(const float4*)(xbase + (size_t)min(rb + 8 + r, KK - 1) * DD + lane * 4);
        }

        // fragments from LDS (2-way banks) + 8 MFMA
        f32x4 acc = {bias, bias, bias, bias};
        #pragma unroll
        for (int s = 0; s < 8; ++s) {
            const bf16x8 afr = *(const bf16x8*)(xsw + col * 512 + ((s * 64 + kg * 16) ^ rswz));
            acc = __builtin_amdgcn_mfma_f32_16x16x32_bf16(afr, bfrag[s], acc, 0, 0, 0);
        }

        // C/D: lane (col,kg), reg r -> e[row = t*16 + kg*4 + r][col]
        if (col < AA) {
            const int row = t * 16 + kg * 4;
            if (row + 3 < KK)                         // row%4==0 -> full-or-none
                *(bf16x4*)&eTb[col * EP + row] = pack4(acc);
        }
    }

    __syncthreads();                                  // eT complete per molecule

    // ---- w2 fragments (deferred: frees 28 VGPRs during Phase A) -------------
    bf16x8 w2f[7];
    #pragma unroll
    for (int ks = 0; ks < 7; ++ks) {
        const int k0 = ks * 32 + kg * 8;
        if (col < AA && k0 < KK) {
            const float* wp = w2 + col * KK + k0;
            w2f[ks] = cvt8(*(const float4*)wp, *(const float4*)(wp + 4));
        } else {
            bf16x8 z;
            #pragma unroll
            for (int j = 0; j < 8; ++j) z[j] = 0;
            w2f[ks] = z;
        }
    }
    const float bc = (col < AA) ? b2[col] : 0.0f;

    // ---- Phase B: r = eT @ w2^T, 7 MFMA k-steps (duplicated by both waves;
    //      identical inputs -> identical bits -> rsw write race is benign) ----
    f32x4 racc = {0.f, 0.f, 0.f, 0.f};
    #pragma unroll
    for (int ks = 0; ks < 7; ++ks) {
        const bf16x8 afr = *(const bf16x8*)&eTb[col * EP + ks * 32 + kg * 8];
        racc = __builtin_amdgcn_mfma_f32_16x16x32_bf16(afr, w2f[ks], racc, 0, 0, 0);
    }
    if (col < AA) {
        #pragma unroll
        for (int r = 0; r < 4; ++r) {
            const int a = kg * 4 + r;                 // D row = a
            if (a < AA) rsw[a * 13 + col] = racc[r] + bc;
        }
    }

    // ---- Phase C: 169 outputs over the molecule's 128 lanes (2 iterations) --
    const int pl = half * 64 + lane;
    for (int p = pl; p < 169; p += 128) {
        const int i  = p / 13;
        const int j  = p - i * 13;
        const int mn = i < j ? i : j;
        const int mx = i < j ? j : i;
        float o[NBOND];
        #pragma unroll
        for (int n = 0; n < NBOND; ++n) o[n] = flb[n];
        #pragma unroll
        for (int c = 0; c < AA; ++c) {
            const float rm = rsw[mn * 13 + c];
            const float rx = rsw[mx * 13 + c];
            #pragma unroll
            for (int n = 0; n < NBOND; ++n)
                o[n] += rm * flw[n * 26 + c] + rx * flw[n * 26 + 13 + c];
        }
        float* op = out + ((size_t)b * 169 + p) * NBOND;
        #pragma unroll
        for (int n = 0; n < NBOND; ++n) op[n] = o[n];
    }
}

extern "C" void kernel_launch(void* const* d_in, const int* in_sizes, int n_in,
                              void* d_out, int out_size, void* d_ws, size_t ws_size,
                              hipStream_t stream) {
    const float* x   = (const float*)d_in[0];
    const float* w1  = (const float*)d_in[1];
    const float* b1  = (const float*)d_in[2];
    const float* w2  = (const float*)d_in[3];
    const float* b2  = (const float*)d_in[4];
    const float* flw = (const float*)d_in[5];
    const float* flb = (const float*)d_in[6];

    fused<<<NBLK, 256, 0, stream>>>(x, w1, b1, w2, b2, flw, flb, (float*)d_out);
}

// Round 2
// 92.601 us; speedup vs baseline: 1.0065x; 1.0065x over previous
//
#include <hip/hip_runtime.h>
#include <cstdint>

#define BB 2048
#define KK 200
#define DD 256
#define AA 13
#define NBOND 5
#define EP 200          // eT bf16 k-pitch (shorts): 400B rows, 16B-aligned
#define NBLK BB         // 1 block = 1 molecule, 3 waves (tiles 5/4/4)

typedef __attribute__((ext_vector_type(8))) short bf16x8;
typedef __attribute__((ext_vector_type(4))) short bf16x4;
typedef __attribute__((ext_vector_type(4))) float f32x4;

// smem layout (bytes). Phase-B fragment reads reach short index 15*EP+223=3223;
// everything in [2600, 3232) is explicitly zeroed (rows 13..15 + tail guard) so
// spill reads are finite zeros (they multiply w2f==0 anyway, but 0*NaN != 0).
//   [0,    6464)  eTb: 16 rows x EP shorts (rows 13..15 = zero guard)
//   [6464, 7140)  rsw: 169 floats
//   [7152, 31728) xs : 3 waves x 16*256 shorts (per-wave x staging)
#define ETB_OFF 0
#define RSW_OFF 6464
#define XS_OFF  7152
#define SMEM_BYTES 31728

// fp32 -> bf16 RNE, branchless (R6 lesson: beats __float22bfloat162_rn+union).
__device__ __forceinline__ short f2bf(float f) {
    unsigned u = __builtin_bit_cast(unsigned, f);
    unsigned r = (u + 0x7fffu + ((u >> 16) & 1u)) >> 16;
    return (short)r;
}

__device__ __forceinline__ bf16x8 cvt8(float4 a, float4 b) {
    bf16x8 f;
    f[0] = f2bf(a.x); f[1] = f2bf(a.y); f[2] = f2bf(a.z); f[3] = f2bf(a.w);
    f[4] = f2bf(b.x); f[5] = f2bf(b.y); f[6] = f2bf(b.z); f[7] = f2bf(b.w);
    return f;
}

__device__ __forceinline__ bf16x4 pack4(f32x4 a) {
    bf16x4 f;
    f[0] = f2bf(a[0]); f[1] = f2bf(a[1]); f[2] = f2bf(a[2]); f[3] = f2bf(a[3]);
    return f;
}

__device__ __forceinline__ bf16x4 pack4f(float4 a) {
    bf16x4 f;
    f[0] = f2bf(a.x); f[1] = f2bf(a.y); f[2] = f2bf(a.z); f[3] = f2bf(a.w);
    return f;
}

// R13: 3 waves per molecule (tiles 0..4 / 5..8 / 9..12), 192-thread blocks,
// grid 2048. launch_bounds(192,3) -> VGPR<=170 -> 12 waves/CU; LDS 31.7KB -> 4
// blocks/CU; grid = 8 blocks/CU of work = 2 BALANCED rounds (R12's 93us was a
// 768+256 tail quantization at 1024 blocks / 3-per-CU capacity, not evidence
// against occupancy). Per-wave Phase A pipeline is byte-identical to the
// 87.5us R11 kernel.
__global__ __launch_bounds__(192, 3) void fused(const float* __restrict__ x,
                                                const float* __restrict__ w1,
                                                const float* __restrict__ b1,
                                                const float* __restrict__ w2,
                                                const float* __restrict__ b2,
                                                const float* __restrict__ flw,
                                                const float* __restrict__ flb,
                                                float* __restrict__ out) {
    __shared__ __align__(16) char smem[SMEM_BYTES];

    const int tid  = threadIdx.x;
    const int lane = tid & 63;
    const int wv   = tid >> 6;         // 0..2, K-tile third
    const int col  = lane & 15;        // fragment row AND output col (a)
    const int kg   = lane >> 4;        // k-group 0..3
    const long b   = blockIdx.x;       // this block's molecule
    const float* xbase = x + b * (size_t)(KK * DD);

    short* eTb = (short*)(smem + ETB_OFF);
    float* rsw = (float*)(smem + RSW_OFF);
    char*  xsw = smem + XS_OFF + wv * (16 * 256 * 2);

    const int T0 = (wv == 0) ? 0 : (wv == 1 ? 5 : 9);
    const int T1 = (wv == 0) ? 5 : (wv == 1 ? 9 : 13);

    // zero guard region [2600, 3232): rows 13..15 + tail, absorbs all Phase-B
    // spill reads (finite zeros; products use w2f==0 or are gated on write)
    for (int i = tid; i < 632; i += 192) eTb[2600 + i] = 0;

    // ---- prologue: first tile of this wave's third, contiguous 1KB loads ----
    float4 xa[8], xb[8];
    {
        const int rb = T0 * 16;
        #pragma unroll
        for (int r = 0; r < 8; ++r)
            xa[r] = *(const float4*)(xbase + (size_t)min(rb + r, KK - 1) * DD + lane * 4);
        #pragma unroll
        for (int r = 0; r < 8; ++r)
            xb[r] = *(const float4*)(xbase + (size_t)min(rb + 8 + r, KK - 1) * DD + lane * 4);
    }

    // ---- W1 B-fragments resident, natural k-order (lane holds W1^T[k][col]) -
    bf16x8 bfrag[8];
    if (col < AA) {
        const float* wp = w1 + col * DD + kg * 8;
        #pragma unroll
        for (int ks = 0; ks < 8; ++ks)
            bfrag[ks] = cvt8(*(const float4*)(wp + ks * 32),
                             *(const float4*)(wp + ks * 32 + 4));
    } else {
        #pragma unroll
        for (int ks = 0; ks < 8; ++ks) {
            bf16x8 z;
            #pragma unroll
            for (int j = 0; j < 8; ++j) z[j] = 0;
            bfrag[ks] = z;
        }
    }
    const float bias = (col < AA) ? b1[col] : 0.0f;

    const int wbyte = lane * 8;                       // unswizzled write chunk
    const int rswz  = (col & 7) << 4;                 // read swizzle constant

    // ---- Phase A: this wave's tiles; regs are the double-buffer across tiles -
    for (int t = T0; t < T1; ++t) {
        // cvt + swizzled ds_write (waits xa loads, then xb loads)
        #pragma unroll
        for (int r = 0; r < 8; ++r)
            *(bf16x4*)(xsw + r * 512 + (wbyte ^ ((r & 7) << 4))) = pack4f(xa[r]);
        #pragma unroll
        for (int r = 0; r < 8; ++r) {
            const int rr = 8 + r;
            *(bf16x4*)(xsw + rr * 512 + (wbyte ^ ((rr & 7) << 4))) = pack4f(xb[r]);
        }

        // issue next tile's 16 contiguous loads (fly through MFMA phase)
        if (t + 1 < T1) {
            const int rb = (t + 1) * 16;
            #pragma unroll
            for (int r = 0; r < 8; ++r)
                xa[r] = *(const float4*)(xbase + (size_t)min(rb + r, KK - 1) * DD + lane * 4);
            #pragma unroll
            for (int r = 0; r < 8; ++r)
                xb[r] = *(const float4*)(xbase + (size_t)min(rb + 8 + r, KK - 1) * DD + lane * 4);
        }

        // fragments from LDS (2-way banks) + 8 MFMA
        f32x4 acc = {bias, bias, bias, bias};
        #pragma unroll
        for (int s = 0; s < 8; ++s) {
            const bf16x8 afr = *(const bf16x8*)(xsw + col * 512 + ((s * 64 + kg * 16) ^ rswz));
            acc = __builtin_amdgcn_mfma_f32_16x16x32_bf16(afr, bfrag[s], acc, 0, 0, 0);
        }

        // C/D: lane (col,kg), reg r -> e[row = t*16 + kg*4 + r][col]
        if (col < AA) {
            const int row = t * 16 + kg * 4;
            if (row + 3 < KK)                         // row%4==0 -> full-or-none
                *(bf16x4*)&eTb[col * EP + row] = pack4(acc);
        }
    }

    __syncthreads();                                  // eT complete

    // ---- w2 fragments (deferred: frees 28 VGPRs during Phase A) -------------
    bf16x8 w2f[7];
    #pragma unroll
    for (int ks = 0; ks < 7; ++ks) {
        const int k0 = ks * 32 + kg * 8;
        if (col < AA && k0 < KK) {
            const float* wp = w2 + col * KK + k0;
            w2f[ks] = cvt8(*(const float4*)wp, *(const float4*)(wp + 4));
        } else {
            bf16x8 z;
            #pragma unroll
            for (int j = 0; j < 8; ++j) z[j] = 0;
            w2f[ks] = z;
        }
    }
    const float bc = (col < AA) ? b2[col] : 0.0f;

    // ---- Phase B: r = eT @ w2^T, 7 MFMA k-steps (duplicated by all 3 waves;
    //      identical inputs -> identical bits -> rsw write race is benign) ----
    f32x4 racc = {0.f, 0.f, 0.f, 0.f};
    #pragma unroll
    for (int ks = 0; ks < 7; ++ks) {
        const bf16x8 afr = *(const bf16x8*)&eTb[col * EP + ks * 32 + kg * 8];
        racc = __builtin_amdgcn_mfma_f32_16x16x32_bf16(afr, w2f[ks], racc, 0, 0, 0);
    }
    if (col < AA) {
        #pragma unroll
        for (int r = 0; r < 4; ++r) {
            const int a = kg * 4 + r;                 // D row = a
            if (a < AA) rsw[a * 13 + col] = racc[r] + bc;
        }
    }

    // ---- Phase C: 169 outputs, one pass over the block's 192 lanes ----------
    {
        const int p = tid;
        if (p < 169) {
            const int i  = p / 13;
            const int j  = p - i * 13;
            const int mn = i < j ? i : j;
            const int mx = i < j ? j : i;
            float o[NBOND];
            #pragma unroll
            for (int n = 0; n < NBOND; ++n) o[n] = flb[n];
            #pragma unroll
            for (int c = 0; c < AA; ++c) {
                const float rm = rsw[mn * 13 + c];
                const float rx = rsw[mx * 13 + c];
                #pragma unroll
                for (int n = 0; n < NBOND; ++n)
                    o[n] += rm * flw[n * 26 + c] + rx * flw[n * 26 + 13 + c];
            }
            float* op = out + ((size_t)b * 169 + p) * NBOND;
            #pragma unroll
            for (int n = 0; n < NBOND; ++n) op[n] = o[n];
        }
    }
}

extern "C" void kernel_launch(void* const* d_in, const int* in_sizes, int n_in,
                              void* d_out, int out_size, void* d_ws, size_t ws_size,
                              hipStream_t stream) {
    const float* x   = (const float*)d_in[0];
    const float* w1  = (const float*)d_in[1];
    const float* b1  = (const float*)d_in[2];
    const float* w2  = (const float*)d_in[3];
    const float* b2  = (const float*)d_in[4];
    const float* flw = (const float*)d_in[5];
    const float* flb = (const float*)d_in[6];

    fused<<<NBLK, 192, 0, stream>>>(x, w1, b1, w2, b2, flw, flb, (float*)d_out);
}

// Round 3
// 83.037 us; speedup vs baseline: 1.1224x; 1.1152x over previous
//
#include <hip/hip_runtime.h>
#include <cstdint>

#define BB 2048
#define KK 200
#define DD 256
#define AA 13
#define NBOND 5
#define EP 216          // eT bf16 k-pitch (shorts): %8==0 (16B align), ~2-way banks
#define NBLK (BB / 4)   // 512 blocks x 4 waves = 2048 waves = 1 molecule/wave

typedef __attribute__((ext_vector_type(8))) short bf16x8;
typedef __attribute__((ext_vector_type(4))) short bf16x4;
typedef __attribute__((ext_vector_type(4))) float f32x4;

// fp32 -> bf16 RNE, branchless (R6 lesson: beats __float22bfloat162_rn+union).
__device__ __forceinline__ short f2bf(float f) {
    unsigned u = __builtin_bit_cast(unsigned, f);
    unsigned r = (u + 0x7fffu + ((u >> 16) & 1u)) >> 16;
    return (short)r;
}

__device__ __forceinline__ bf16x8 cvt8(float4 a, float4 b) {
    bf16x8 f;
    f[0] = f2bf(a.x); f[1] = f2bf(a.y); f[2] = f2bf(a.z); f[3] = f2bf(a.w);
    f[4] = f2bf(b.x); f[5] = f2bf(b.y); f[6] = f2bf(b.z); f[7] = f2bf(b.w);
    return f;
}

__device__ __forceinline__ bf16x4 pack4(f32x4 a) {
    bf16x4 f;
    f[0] = f2bf(a[0]); f[1] = f2bf(a[1]); f[2] = f2bf(a[2]); f[3] = f2bf(a[3]);
    return f;
}

__device__ __forceinline__ bf16x4 pack4f(float4 a) {
    bf16x4 f;
    f[0] = f2bf(a.x); f[1] = f2bf(a.y); f[2] = f2bf(a.z); f[3] = f2bf(a.w);
    return f;
}

// R14: revert to R11's 1-wave-per-molecule structure (R12/R13 proved splitting
// costs ~5us and 12 waves/CU does NOT close the BW gap). Single change vs R11:
// 2-TILE-DEEP register prefetch. Two 16xfloat4 buffers; ds_write of tile t
// retires t's loads under a counted vmcnt(16) while t+1's batch stays in
// flight and t+2's batch issues right after. Per-wave outstanding never drops
// to 0 (R11 had a ~500-cyc zero-outstanding hole per tile during cvt+ds_write,
// draining the HBM queue). t-loop fully unrolled so buffer choice is static
// (rule #20: runtime-indexed reg arrays spill to scratch). w2f deferred past
// Phase A (bit-identical, proven in R12/R13) to keep VGPR under the 256 cap.
__global__ __launch_bounds__(256, 2) void fused(const float* __restrict__ x,
                                                const float* __restrict__ w1,
                                                const float* __restrict__ b1,
                                                const float* __restrict__ w2,
                                                const float* __restrict__ b2,
                                                const float* __restrict__ flw,
                                                const float* __restrict__ flb,
                                                float* __restrict__ out) {
    __shared__ __align__(16) short xs[4][16 * 256];  // 32 KB: 8KB/wave x-stage
    __shared__ __align__(16) short eTb[4][16][EP];   // 27.6 KB
    __shared__ float rsw[4][169];                    // per-wave r buffer

    const int tid  = threadIdx.x;
    const int lane = tid & 63;
    const int wv   = tid >> 6;
    const int col  = lane & 15;        // fragment row AND output col (a)
    const int kg   = lane >> 4;        // k-group 0..3
    const long b   = (long)blockIdx.x * 4 + wv;      // this wave's molecule
    const float* xbase = x + b * (size_t)(KK * DD);

    // ---- prologue: tiles 0 and 1, contiguous loads (uniform base + lane*16B)
    float4 tA[16], tB[16];
    #pragma unroll
    for (int r = 0; r < 16; ++r)
        tA[r] = *(const float4*)(xbase + (size_t)r * DD + lane * 4);
    #pragma unroll
    for (int r = 0; r < 16; ++r)
        tB[r] = *(const float4*)(xbase + (size_t)(16 + r) * DD + lane * 4);

    // ---- W1 B-fragments resident, natural k-order (lane holds W1^T[k][col]) -
    bf16x8 bfrag[8];
    if (col < AA) {
        const float* wp = w1 + col * DD + kg * 8;
        #pragma unroll
        for (int ks = 0; ks < 8; ++ks)
            bfrag[ks] = cvt8(*(const float4*)(wp + ks * 32),
                             *(const float4*)(wp + ks * 32 + 4));
    } else {
        #pragma unroll
        for (int ks = 0; ks < 8; ++ks) {
            bf16x8 z;
            #pragma unroll
            for (int j = 0; j < 8; ++j) z[j] = 0;
            bfrag[ks] = z;
        }
    }
    const float bias = (col < AA) ? b1[col] : 0.0f;

    // ---- zero this wave's eT pad regions ------------------------------------
    for (int i = lane; i < 256; i += 64) {            // rows 0..15, k 200..215
        eTb[wv][i >> 4][200 + (i & 15)] = 0;
    }
    for (int i = lane; i < 600; i += 64) {            // rows 13..15, k 0..199
        eTb[wv][13 + i / 200][i % 200] = 0;
    }

    char* xsw = (char*)&xs[wv][0];
    const int wbyte = lane * 8;                       // unswizzled write chunk
    const int rswz  = (col & 7) << 4;                 // read swizzle constant

    // ---- Phase A: 13 tiles, 2-deep pipelined, statically unrolled -----------
    // TILE_STEP(BUF, T): ds_write tile T from BUF (vmcnt retires only T's
    // loads; T+1's stay outstanding), reload BUF with tile T+2, then MFMA.
#define TILE_STEP(BUF, T)                                                      \
    {                                                                          \
        _Pragma("unroll")                                                      \
        for (int r = 0; r < 16; ++r)                                           \
            *(bf16x4*)(xsw + r * 512 + (wbyte ^ ((r & 7) << 4))) =             \
                pack4f(BUF[r]);                                                \
        if ((T) + 2 < 13) {                                                    \
            const int rb = ((T) + 2) * 16;                                     \
            _Pragma("unroll")                                                  \
            for (int r = 0; r < 16; ++r)                                       \
                BUF[r] = *(const float4*)(xbase +                              \
                    (size_t)min(rb + r, KK - 1) * DD + lane * 4);              \
        }                                                                      \
        f32x4 acc = {bias, bias, bias, bias};                                  \
        _Pragma("unroll")                                                      \
        for (int s = 0; s < 8; ++s) {                                          \
            const bf16x8 afr = *(const bf16x8*)(xsw + col * 512 +              \
                ((s * 64 + kg * 16) ^ rswz));                                  \
            acc = __builtin_amdgcn_mfma_f32_16x16x32_bf16(afr, bfrag[s], acc,  \
                                                          0, 0, 0);            \
        }                                                                      \
        if (col < AA) {                                                        \
            const int row = (T) * 16 + kg * 4;                                 \
            if (row + 3 < KK)                                                  \
                *(bf16x4*)&eTb[wv][col][row] = pack4(acc);                     \
        }                                                                      \
    }

    TILE_STEP(tA, 0)
    TILE_STEP(tB, 1)
    TILE_STEP(tA, 2)
    TILE_STEP(tB, 3)
    TILE_STEP(tA, 4)
    TILE_STEP(tB, 5)
    TILE_STEP(tA, 6)
    TILE_STEP(tB, 7)
    TILE_STEP(tA, 8)
    TILE_STEP(tB, 9)
    TILE_STEP(tA, 10)
    TILE_STEP(tB, 11)
    TILE_STEP(tA, 12)
#undef TILE_STEP

    // ---- w2 fragments (deferred: frees Phase-A registers; bit-identical) ----
    bf16x8 w2f[7];
    #pragma unroll
    for (int ks = 0; ks < 7; ++ks) {
        const int k0 = ks * 32 + kg * 8;
        if (col < AA && k0 < KK) {
            const float* wp = w2 + col * KK + k0;
            w2f[ks] = cvt8(*(const float4*)wp, *(const float4*)(wp + 4));
        } else {
            bf16x8 z;
            #pragma unroll
            for (int j = 0; j < 8; ++j) z[j] = 0;
            w2f[ks] = z;
        }
    }
    const float bc = (col < AA) ? b2[col] : 0.0f;

    // ---- Phase B: r = eT @ w2^T, 7 MFMA k-steps (lgkm orders LDS, no bar) ---
    f32x4 racc = {0.f, 0.f, 0.f, 0.f};
    #pragma unroll
    for (int ks = 0; ks < 7; ++ks) {
        const bf16x8 afr = *(const bf16x8*)&eTb[wv][col][ks * 32 + kg * 8];
        racc = __builtin_amdgcn_mfma_f32_16x16x32_bf16(afr, w2f[ks], racc, 0, 0, 0);
    }
    if (col < AA) {
        #pragma unroll
        for (int r = 0; r < 4; ++r) {
            const int a = kg * 4 + r;                 // D row = a
            if (a < AA) rsw[wv][a * 13 + col] = racc[r] + bc;
        }
    }

    // ---- Phase C: 169 outputs over 3 lane-iterations ------------------------
    for (int p = lane; p < 169; p += 64) {
        const int i  = p / 13;
        const int j  = p - i * 13;
        const int mn = i < j ? i : j;
        const int mx = i < j ? j : i;
        float o[NBOND];
        #pragma unroll
        for (int n = 0; n < NBOND; ++n) o[n] = flb[n];
        #pragma unroll
        for (int c = 0; c < AA; ++c) {
            const float rm = rsw[wv][mn * 13 + c];
            const float rx = rsw[wv][mx * 13 + c];
            #pragma unroll
            for (int n = 0; n < NBOND; ++n)
                o[n] += rm * flw[n * 26 + c] + rx * flw[n * 26 + 13 + c];
        }
        float* op = out + ((size_t)b * 169 + p) * NBOND;
        #pragma unroll
        for (int n = 0; n < NBOND; ++n) op[n] = o[n];
    }
}

extern "C" void kernel_launch(void* const* d_in, const int* in_sizes, int n_in,
                              void* d_out, int out_size, void* d_ws, size_t ws_size,
                              hipStream_t stream) {
    const float* x   = (const float*)d_in[0];
    const float* w1  = (const float*)d_in[1];
    const float* b1  = (const float*)d_in[2];
    const float* w2  = (const float*)d_in[3];
    const float* b2  = (const float*)d_in[4];
    const float* flw = (const float*)d_in[5];
    const float* flb = (const float*)d_in[6];

    fused<<<NBLK, 256, 0, stream>>>(x, w1, b1, w2, b2, flw, flb, (float*)d_out);
}

// Round 4
// 71.927 us; speedup vs baseline: 1.2958x; 1.1545x over previous
//
#include <hip/hip_runtime.h>
#include <cstdint>

#define BB 2048
#define KK 200
#define DD 256
#define AA 13
#define NBOND 5
#define EP 216          // eT bf16 k-pitch (shorts): %8==0 (16B align), ~2-way banks
#define NBLK (BB / 4)   // 512 blocks x 4 waves = 2048 waves = 1 molecule/wave

typedef __attribute__((ext_vector_type(8))) short bf16x8;
typedef __attribute__((ext_vector_type(4))) short bf16x4;
typedef __attribute__((ext_vector_type(4))) float f32x4;

// fp32 -> bf16 RNE, branchless (R6 lesson: beats __float22bfloat162_rn+union).
__device__ __forceinline__ short f2bf(float f) {
    unsigned u = __builtin_bit_cast(unsigned, f);
    unsigned r = (u + 0x7fffu + ((u >> 16) & 1u)) >> 16;
    return (short)r;
}

__device__ __forceinline__ bf16x8 cvt8(float4 a, float4 b) {
    bf16x8 f;
    f[0] = f2bf(a.x); f[1] = f2bf(a.y); f[2] = f2bf(a.z); f[3] = f2bf(a.w);
    f[4] = f2bf(b.x); f[5] = f2bf(b.y); f[6] = f2bf(b.z); f[7] = f2bf(b.w);
    return f;
}

__device__ __forceinline__ bf16x4 pack4(f32x4 a) {
    bf16x4 f;
    f[0] = f2bf(a[0]); f[1] = f2bf(a[1]); f[2] = f2bf(a[2]); f[3] = f2bf(a[3]);
    return f;
}

// R15: R14 structure (2-deep reg pipeline, 83.0us) + three L2-path probes:
//  (1) NONTEMPORAL loads for x -- 419MB read exactly once, streams through
//      L2/L3 with full read-allocate; nt marks lines evict-first. Weights
//      keep the cached path (reused by all 512 blocks).
//  (2) NONTEMPORAL stores for out (written once, never read back).
//  (3) tile-12 clamped loads trimmed (was: 8x re-read of row 199 per wave =
//      16MB L2-hit traffic + issue slots). Stale finite register data feeds
//      MFMA rows that the row+3<KK gate discards.
// Supply-side is saturated (128-256KB outstanding/CU vs 9.2KB BDP), so depth-3
// is NOT attempted (predicts ~0, VGPR>256). If this probe is neutral, the
// steady state is at its pattern ceiling and only the ~4-5us head/tail remains.
__global__ __launch_bounds__(256, 2) void fused(const float* __restrict__ x,
                                                const float* __restrict__ w1,
                                                const float* __restrict__ b1,
                                                const float* __restrict__ w2,
                                                const float* __restrict__ b2,
                                                const float* __restrict__ flw,
                                                const float* __restrict__ flb,
                                                float* __restrict__ out) {
    __shared__ __align__(16) short xs[4][16 * 256];  // 32 KB: 8KB/wave x-stage
    __shared__ __align__(16) short eTb[4][16][EP];   // 27.6 KB
    __shared__ float rsw[4][169];                    // per-wave r buffer

    const int tid  = threadIdx.x;
    const int lane = tid & 63;
    const int wv   = tid >> 6;
    const int col  = lane & 15;        // fragment row AND output col (a)
    const int kg   = lane >> 4;        // k-group 0..3
    const long b   = (long)blockIdx.x * 4 + wv;      // this wave's molecule
    const float* xbase = x + b * (size_t)(KK * DD);

    // ---- prologue: tiles 0 and 1, contiguous NT loads -----------------------
    f32x4 tA[16], tB[16];
    #pragma unroll
    for (int r = 0; r < 16; ++r)
        tA[r] = __builtin_nontemporal_load(
            (const f32x4*)(xbase + (size_t)r * DD + lane * 4));
    #pragma unroll
    for (int r = 0; r < 16; ++r)
        tB[r] = __builtin_nontemporal_load(
            (const f32x4*)(xbase + (size_t)(16 + r) * DD + lane * 4));

    // ---- W1 B-fragments resident, natural k-order (lane holds W1^T[k][col]) -
    bf16x8 bfrag[8];
    if (col < AA) {
        const float* wp = w1 + col * DD + kg * 8;
        #pragma unroll
        for (int ks = 0; ks < 8; ++ks)
            bfrag[ks] = cvt8(*(const float4*)(wp + ks * 32),
                             *(const float4*)(wp + ks * 32 + 4));
    } else {
        #pragma unroll
        for (int ks = 0; ks < 8; ++ks) {
            bf16x8 z;
            #pragma unroll
            for (int j = 0; j < 8; ++j) z[j] = 0;
            bfrag[ks] = z;
        }
    }
    const float bias = (col < AA) ? b1[col] : 0.0f;

    // ---- zero this wave's eT pad regions ------------------------------------
    for (int i = lane; i < 256; i += 64) {            // rows 0..15, k 200..215
        eTb[wv][i >> 4][200 + (i & 15)] = 0;
    }
    for (int i = lane; i < 600; i += 64) {            // rows 13..15, k 0..199
        eTb[wv][13 + i / 200][i % 200] = 0;
    }

    char* xsw = (char*)&xs[wv][0];
    const int wbyte = lane * 8;                       // unswizzled write chunk
    const int rswz  = (col & 7) << 4;                 // read swizzle constant

    // ---- Phase A: 13 tiles, 2-deep pipelined, statically unrolled -----------
    // TILE_STEP(BUF, T): ds_write tile T from BUF (vmcnt retires only T's
    // loads; T+1's stay outstanding), reload BUF with tile T+2 (NT, per-row
    // compile-time bounds guard: tile 12 loads only its 8 real rows), MFMA.
#define TILE_STEP(BUF, T)                                                      \
    {                                                                          \
        _Pragma("unroll")                                                      \
        for (int r = 0; r < 16; ++r)                                           \
            *(bf16x4*)(xsw + r * 512 + (wbyte ^ ((r & 7) << 4))) =             \
                pack4(BUF[r]);                                                 \
        if ((T) + 2 < 13) {                                                    \
            const int rb = ((T) + 2) * 16;                                     \
            _Pragma("unroll")                                                  \
            for (int r = 0; r < 16; ++r)                                       \
                if (rb + r < KK)                                               \
                    BUF[r] = __builtin_nontemporal_load(                       \
                        (const f32x4*)(xbase + (size_t)(rb + r) * DD +         \
                                       lane * 4));                             \
        }                                                                      \
        f32x4 acc = {bias, bias, bias, bias};                                  \
        _Pragma("unroll")                                                      \
        for (int s = 0; s < 8; ++s) {                                          \
            const bf16x8 afr = *(const bf16x8*)(xsw + col * 512 +              \
                ((s * 64 + kg * 16) ^ rswz));                                  \
            acc = __builtin_amdgcn_mfma_f32_16x16x32_bf16(afr, bfrag[s], acc,  \
                                                          0, 0, 0);            \
        }                                                                      \
        if (col < AA) {                                                        \
            const int row = (T) * 16 + kg * 4;                                 \
            if (row + 3 < KK)                                                  \
                *(bf16x4*)&eTb[wv][col][row] = pack4(acc);                     \
        }                                                                      \
    }

    TILE_STEP(tA, 0)
    TILE_STEP(tB, 1)
    TILE_STEP(tA, 2)
    TILE_STEP(tB, 3)
    TILE_STEP(tA, 4)
    TILE_STEP(tB, 5)
    TILE_STEP(tA, 6)
    TILE_STEP(tB, 7)
    TILE_STEP(tA, 8)
    TILE_STEP(tB, 9)
    TILE_STEP(tA, 10)
    TILE_STEP(tB, 11)
    TILE_STEP(tA, 12)
#undef TILE_STEP

    // ---- w2 fragments (deferred: frees Phase-A registers; bit-identical) ----
    bf16x8 w2f[7];
    #pragma unroll
    for (int ks = 0; ks < 7; ++ks) {
        const int k0 = ks * 32 + kg * 8;
        if (col < AA && k0 < KK) {
            const float* wp = w2 + col * KK + k0;
            w2f[ks] = cvt8(*(const float4*)wp, *(const float4*)(wp + 4));
        } else {
            bf16x8 z;
            #pragma unroll
            for (int j = 0; j < 8; ++j) z[j] = 0;
            w2f[ks] = z;
        }
    }
    const float bc = (col < AA) ? b2[col] : 0.0f;

    // ---- Phase B: r = eT @ w2^T, 7 MFMA k-steps (lgkm orders LDS, no bar) ---
    f32x4 racc = {0.f, 0.f, 0.f, 0.f};
    #pragma unroll
    for (int ks = 0; ks < 7; ++ks) {
        const bf16x8 afr = *(const bf16x8*)&eTb[wv][col][ks * 32 + kg * 8];
        racc = __builtin_amdgcn_mfma_f32_16x16x32_bf16(afr, w2f[ks], racc, 0, 0, 0);
    }
    if (col < AA) {
        #pragma unroll
        for (int r = 0; r < 4; ++r) {
            const int a = kg * 4 + r;                 // D row = a
            if (a < AA) rsw[wv][a * 13 + col] = racc[r] + bc;
        }
    }

    // ---- Phase C: 169 outputs over 3 lane-iterations, NT stores -------------
    for (int p = lane; p < 169; p += 64) {
        const int i  = p / 13;
        const int j  = p - i * 13;
        const int mn = i < j ? i : j;
        const int mx = i < j ? j : i;
        float o[NBOND];
        #pragma unroll
        for (int n = 0; n < NBOND; ++n) o[n] = flb[n];
        #pragma unroll
        for (int c = 0; c < AA; ++c) {
            const float rm = rsw[wv][mn * 13 + c];
            const float rx = rsw[wv][mx * 13 + c];
            #pragma unroll
            for (int n = 0; n < NBOND; ++n)
                o[n] += rm * flw[n * 26 + c] + rx * flw[n * 26 + 13 + c];
        }
        float* op = out + ((size_t)b * 169 + p) * NBOND;
        #pragma unroll
        for (int n = 0; n < NBOND; ++n)
            __builtin_nontemporal_store(o[n], op + n);
    }
}

extern "C" void kernel_launch(void* const* d_in, const int* in_sizes, int n_in,
                              void* d_out, int out_size, void* d_ws, size_t ws_size,
                              hipStream_t stream) {
    const float* x   = (const float*)d_in[0];
    const float* w1  = (const float*)d_in[1];
    const float* b1  = (const float*)d_in[2];
    const float* w2  = (const float*)d_in[3];
    const float* b2  = (const float*)d_in[4];
    const float* flw = (const float*)d_in[5];
    const float* flb = (const float*)d_in[6];

    fused<<<NBLK, 256, 0, stream>>>(x, w1, b1, w2, b2, flw, flb, (float*)d_out);
}